// Round 8
// baseline (68.065 us; speedup 1.0000x reference)
//
#include <hip/hip_runtime.h>

// DeepWalk hierarchical-softmax forward — round 6.
// Change vs R3 (48.2us best): process elements in context-sorted order.
// A 3-kernel counting sort (hist -> scan -> scatter, by context's top 10
// bits, 1024 buckets) builds a permutation in d_ws; the main kernel walks
// elements bucket-by-bucket. Within a bucket (~64 elems spanning 512 leaves)
// levels shift>=9 collapse to 1-2 distinct rows and shift 6-8 to <=8 rows,
// so ~435MB of logical gather traffic moves from L3 (~13 TB/s measured) to
// L1/L2. XCD-chunked block swizzle gives each XCD's L2 a contiguous bucket
// range. Falls back to direct order if ws_size < 266KB.

#define HS_NUM_NODES (1 << 19)
#define HS_LVLS 18          // levels i = 1 .. 18  (L = 19)
#define HS_NBKT 1024
#define HS_BSH  9           // context in [0,2^19): bucket = context >> 9

template <int N, int M>
__device__ inline void fold_step(float* w, int sub) {
    const bool hi = (sub & M) != 0;
    constexpr int NN = (N + 1) / 2;
#pragma unroll
    for (int k = 0; k < NN; ++k) {
        const float a = w[2 * k];
        const float b = (2 * k + 1 < N) ? w[2 * k + 1] : 0.f;
        const float keep = hi ? b : a;
        const float send = hi ? a : b;
        w[k] = keep + __shfl_xor(send, M, 64);   // M<=16: stays in half-wave
    }
}

__global__ void hs_hist(const int* __restrict__ ctx, int B,
                        int* __restrict__ hist) {
    const int i = blockIdx.x * blockDim.x + threadIdx.x;
    if (i < B) atomicAdd(&hist[ctx[i] >> HS_BSH], 1);
}

__global__ __launch_bounds__(HS_NBKT) void hs_scan(int* __restrict__ hist) {
    __shared__ int a[HS_NBKT], b[HS_NBKT];
    const int t = threadIdx.x;
    const int orig = hist[t];
    a[t] = orig;
    __syncthreads();
    int* src = a; int* dst = b;
#pragma unroll
    for (int off = 1; off < HS_NBKT; off <<= 1) {
        dst[t] = (t >= off) ? (src[t] + src[t - off]) : src[t];
        __syncthreads();
        int* tmp = src; src = dst; dst = tmp;
    }
    hist[t] = src[t] - orig;   // exclusive prefix sum
}

__global__ void hs_scatter(const int* __restrict__ ctx, int B,
                           int* __restrict__ off, int* __restrict__ perm) {
    const int i = blockIdx.x * blockDim.x + threadIdx.x;
    if (i < B) {
        const int p = atomicAdd(&off[ctx[i] >> HS_BSH], 1);
        perm[p] = i;
    }
}

// perm==nullptr -> direct (fallback) ordering.
__global__ __launch_bounds__(256) void hs_fwd_kernel(
    const int* __restrict__ center,
    const int* __restrict__ context,
    const float* __restrict__ emb,
    const float* __restrict__ probs,
    const int* __restrict__ perm,
    float* __restrict__ out,
    int B)
{
    // XCD-chunked swizzle: each XCD gets a contiguous chunk of sorted order.
    int bid = blockIdx.x;
    const int nb = gridDim.x;
    if ((nb & 7) == 0) bid = (bid & 7) * (nb >> 3) + (bid >> 3);

    const int slot = bid * (blockDim.x >> 5) + (threadIdx.x >> 5);
    if (slot >= B) return;
    const int elem = perm ? perm[slot] : slot;
    const int sub  = threadIdx.x & 31;

    const int c   = center[elem];
    const int ctx = context[elem] + HS_NUM_NODES;

    const float4 ec =
        *reinterpret_cast<const float4*>(emb + (size_t)c * 128 + sub * 4);

    float4 p[HS_LVLS];
#pragma unroll
    for (int i = 0; i < HS_LVLS; ++i) {
        const int node = ctx >> (i + 1);
        p[i] = *reinterpret_cast<const float4*>(
            probs + (size_t)node * 128 + sub * 4);
    }

    float w[HS_LVLS];
#pragma unroll
    for (int i = 0; i < HS_LVLS; ++i)
        w[i] = p[i].x * ec.x + p[i].y * ec.y + p[i].z * ec.z + p[i].w * ec.w;

    fold_step<18, 1>(w, sub);
    fold_step<9,  2>(w, sub);
    fold_step<5,  4>(w, sub);
    fold_step<3,  8>(w, sub);
    fold_step<2, 16>(w, sub);

    const int sh   = (sub < HS_LVLS) ? (sub + 1) : 1;
    const int node = ctx >> sh;
    const float S  = w[0];
    const float x  = (node & 1) ? -S : S;
    float ls = fminf(x, 0.f) - __logf(1.f + __expf(-fabsf(x)));
    ls = (sub < HS_LVLS) ? ls : 0.f;

    float acc = ls;
#pragma unroll
    for (int m = 16; m; m >>= 1) acc += __shfl_xor(acc, m, 64);

    if (sub == 0) out[elem] = -acc;
}

extern "C" void kernel_launch(void* const* d_in, const int* in_sizes, int n_in,
                              void* d_out, int out_size, void* d_ws, size_t ws_size,
                              hipStream_t stream) {
    const int*   center  = (const int*)d_in[0];
    const int*   context = (const int*)d_in[1];
    const float* emb     = (const float*)d_in[2];
    const float* probs   = (const float*)d_in[3];
    float*       out     = (float*)d_out;

    const int B = in_sizes[0];                 // 65536
    const int threads = 256;                   // 8 elements / block
    const int blocks  = (B * 32 + threads - 1) / threads;

    const size_t ws_need = (size_t)(HS_NBKT + B) * sizeof(int);
    int* perm = nullptr;
    if (ws_size >= ws_need) {
        int* hist = (int*)d_ws;          // [0, 1024): counts -> offsets
        perm      = hist + HS_NBKT;      // [1024, 1024+B): sorted elem ids
        hipMemsetAsync(hist, 0, HS_NBKT * sizeof(int), stream);
        hs_hist   <<<(B + 255) / 256, 256, 0, stream>>>(context, B, hist);
        hs_scan   <<<1, HS_NBKT, 0, stream>>>(hist);
        hs_scatter<<<(B + 255) / 256, 256, 0, stream>>>(context, B, hist, perm);
    }

    hs_fwd_kernel<<<blocks, threads, 0, stream>>>(center, context, emb, probs,
                                                  perm, out, B);
}

// Round 9
// 49.996 us; speedup vs baseline: 1.3614x; 1.3614x over previous
//
#include <hip/hip_runtime.h>

// DeepWalk hierarchical-softmax forward — round 7.
// Change vs R3 (48.2us best): pin the shallow tree levels in LDS.
// Evidence: sort-for-locality gave ZERO main-kernel gain (R6) -> caches can't
// capture the shallow-level reuse because the deep-level stream sweeps L1
// every ~2 waves and L2 every ~2.4us. LDS is swept by nothing.
// All nodes for shifts 13..18 lie in rows [2,128) of probs_tensor:
// 126 rows x 512B = 63KB static LDS. Each block copies that range once
// (coalesced, self-L3-warming across blocks), then 6 of the 18 level
// gathers (~33% of gather traffic, ~201MB logical) become ds_read_b128
// with zero VM transactions. Grid: 256 blocks x 1024 threads, grid-stride;
// 32-lane groups + R3's fold butterfly unchanged.

#define HS_NUM_NODES (1 << 19)
#define HS_LVLS 18          // levels i = 1 .. 18  (L = 19)
#define HS_GLB  12          // levels with shift 1..12: global gathers
#define HS_LDSL 6           // levels with shift 13..18: LDS (rows [2,128))
#define HS_LDS_FLOATS (126 * 128)   // 63KB

template <int N, int M>
__device__ inline void fold_step(float* w, int sub) {
    const bool hi = (sub & M) != 0;
    constexpr int NN = (N + 1) / 2;
#pragma unroll
    for (int k = 0; k < NN; ++k) {
        const float a = w[2 * k];
        const float b = (2 * k + 1 < N) ? w[2 * k + 1] : 0.f;
        const float keep = hi ? b : a;
        const float send = hi ? a : b;
        w[k] = keep + __shfl_xor(send, M, 64);   // M<=16: stays in 32-group
    }
}

__global__ __launch_bounds__(1024) void hs_fwd_kernel(
    const int* __restrict__ center,
    const int* __restrict__ context,
    const float* __restrict__ emb,
    const float* __restrict__ probs,
    float* __restrict__ out,
    int B)
{
    __shared__ float lds[HS_LDS_FLOATS];

    // Cooperative preload of probs rows [2,128) -> LDS (contiguous, coalesced).
    {
        const float4* src = reinterpret_cast<const float4*>(probs) + 64; // row 2
        float4*       dst = reinterpret_cast<float4*>(lds);
        for (int k = threadIdx.x; k < HS_LDS_FLOATS / 4; k += 1024)
            dst[k] = src[k];
    }
    __syncthreads();

    const int group = threadIdx.x >> 5;     // 0..31 within block
    const int sub   = threadIdx.x & 31;
    const int ngroups = gridDim.x * 32;

    for (int slot = blockIdx.x * 32 + group; slot < B; slot += ngroups) {
        const int c   = center[slot];
        const int ctx = context[slot] + HS_NUM_NODES;

        const float4 ec =
            *reinterpret_cast<const float4*>(emb + (size_t)c * 128 + sub * 4);

        // Deep/mid levels (shift 1..12): global gathers, all issued up front.
        float4 p[HS_GLB];
#pragma unroll
        for (int i = 0; i < HS_GLB; ++i) {
            const int node = ctx >> (i + 1);
            p[i] = *reinterpret_cast<const float4*>(
                probs + (size_t)node * 128 + sub * 4);
        }
        // Shallow levels (shift 13..18): LDS. node in [2,128) -> row node-2.
        float4 q[HS_LDSL];
#pragma unroll
        for (int i = 0; i < HS_LDSL; ++i) {
            const int node = ctx >> (i + 13);
            q[i] = *reinterpret_cast<const float4*>(
                lds + (node - 2) * 128 + sub * 4);
        }

        float w[HS_LVLS];
#pragma unroll
        for (int i = 0; i < HS_GLB; ++i)
            w[i] = p[i].x * ec.x + p[i].y * ec.y + p[i].z * ec.z + p[i].w * ec.w;
#pragma unroll
        for (int i = 0; i < HS_LDSL; ++i)
            w[HS_GLB + i] = q[i].x * ec.x + q[i].y * ec.y
                          + q[i].z * ec.z + q[i].w * ec.w;

        // Multi-value butterfly: lane l ends with the full dot for level l.
        fold_step<18, 1>(w, sub);
        fold_step<9,  2>(w, sub);
        fold_step<5,  4>(w, sub);
        fold_step<3,  8>(w, sub);
        fold_step<2, 16>(w, sub);

        const int sh   = (sub < HS_LVLS) ? (sub + 1) : 1;
        const int node = ctx >> sh;
        const float S  = w[0];
        const float x  = (node & 1) ? -S : S;
        float ls = fminf(x, 0.f) - __logf(1.f + __expf(-fabsf(x)));
        ls = (sub < HS_LVLS) ? ls : 0.f;

        float acc = ls;
#pragma unroll
        for (int m = 16; m; m >>= 1) acc += __shfl_xor(acc, m, 64);

        if (sub == 0) out[slot] = -acc;
    }
}

extern "C" void kernel_launch(void* const* d_in, const int* in_sizes, int n_in,
                              void* d_out, int out_size, void* d_ws, size_t ws_size,
                              hipStream_t stream) {
    const int*   center  = (const int*)d_in[0];
    const int*   context = (const int*)d_in[1];
    const float* emb     = (const float*)d_in[2];
    const float* probs   = (const float*)d_in[3];
    float*       out     = (float*)d_out;

    const int B = in_sizes[0];                 // 65536
    hs_fwd_kernel<<<256, 1024, 0, stream>>>(center, context, emb, probs,
                                            out, B);
}